// Round 1
// baseline (449.714 us; speedup 1.0000x reference)
//
#include <hip/hip_runtime.h>

typedef unsigned short u16;
typedef __bf16 bf16x8 __attribute__((ext_vector_type(8)));
typedef float f32x4 __attribute__((ext_vector_type(4)));

__device__ __forceinline__ u16 f2b(float f) {
    unsigned u = __builtin_bit_cast(unsigned, f);
    unsigned r = (u + 0x7fffu + ((u >> 16) & 1u)) >> 16;
    return (u16)r;
}

// ---------------- convert x (fp32 -> bf16), 8 elems/thread ----------------
__global__ __launch_bounds__(256) void k_convert(const float* __restrict__ in,
                                                 u16* __restrict__ out, int n8) {
    int i = blockIdx.x * 256 + threadIdx.x;
    if (i >= n8) return;
    const float4* p = (const float4*)(in + (size_t)i * 8);
    float4 a = p[0], b = p[1];
    u16 t[8] = {f2b(a.x), f2b(a.y), f2b(a.z), f2b(a.w),
                f2b(b.x), f2b(b.y), f2b(b.z), f2b(b.w)};
    *(uint4*)(out + (size_t)i * 8) = *(const uint4*)t;
}

// -------- transpose + convert: in[R][C] fp32 -> out[C][R] bf16, 64x64 tiles --------
__global__ __launch_bounds__(256) void k_transpose_bf16(const float* __restrict__ in,
                                                        u16* __restrict__ out,
                                                        int R, int C) {
    __shared__ u16 tile[64][72];
    int tc = blockIdx.x * 64;  // C-dim base
    int tr = blockIdx.y * 64;  // R-dim base
    for (int i = threadIdx.x; i < 4096; i += 256) {
        int r = i >> 6, c = i & 63;
        tile[c][r] = f2b(in[(size_t)(tr + r) * C + tc + c]);
    }
    __syncthreads();
    for (int i = threadIdx.x; i < 4096; i += 256) {
        int r = i >> 6, c = i & 63;  // r indexes C, c indexes R
        out[(size_t)(tc + r) * R + tr + c] = tile[r][c];
    }
}

// ---------------- shared 128x128x(K) bf16 MFMA mainloop ----------------
// A: [.. ][K] bf16 rows at Ab (block's 128 rows), Bt: [..][K] bf16 rows at Bb.
// LDS tiles 128 x 32 bf16, row stride 40 (pad 8: 80B = 16B-multiple, 2-way banks).
__device__ __forceinline__ void gemm_mainloop(const u16* __restrict__ Ab,
                                              const u16* __restrict__ Bb, int K,
                                              u16* As, u16* Bs, int tid,
                                              f32x4 (&acc)[4][4]) {
    const int wave = tid >> 6, lane = tid & 63;
    const int col = lane & 15, quad = lane >> 4;
    const int wm = wave >> 1, wn = wave & 1;
    const int r0 = tid >> 2, kc = tid & 3;
    for (int k0 = 0; k0 < K; k0 += 32) {
        if (k0) __syncthreads();
#pragma unroll
        for (int it = 0; it < 2; ++it) {
            int row = r0 + it * 64;
            uint4 av = *(const uint4*)(Ab + (size_t)row * K + k0 + kc * 8);
            uint4 bv = *(const uint4*)(Bb + (size_t)row * K + k0 + kc * 8);
            *(uint4*)(As + row * 40 + kc * 8) = av;
            *(uint4*)(Bs + row * 40 + kc * 8) = bv;
        }
        __syncthreads();
        bf16x8 af[4], bfr[4];
#pragma unroll
        for (int mt = 0; mt < 4; ++mt)
            af[mt] = *(const bf16x8*)(As + (wm * 64 + mt * 16 + col) * 40 + quad * 8);
#pragma unroll
        for (int nt = 0; nt < 4; ++nt)
            bfr[nt] = *(const bf16x8*)(Bs + (wn * 64 + nt * 16 + col) * 40 + quad * 8);
#pragma unroll
        for (int mt = 0; mt < 4; ++mt)
#pragma unroll
            for (int nt = 0; nt < 4; ++nt)
                acc[mt][nt] = __builtin_amdgcn_mfma_f32_16x16x32_bf16(
                    af[mt], bfr[nt], acc[mt][nt], 0, 0, 0);
    }
}

// ---------------- QKV GEMM + bias + RoPE + head reshape ----------------
// A: x_bf [8192][1024], Bt: wqkvT [3072][1024]
// Writes Qr,Kr as [B=4][H=16][S=2048][D=64] bf16 (RoPE applied), Vt as [B][H][D][S] bf16.
__global__ __launch_bounds__(256) void k_gemm_qkv_rope(
    const u16* __restrict__ A, const u16* __restrict__ Bt,
    const float* __restrict__ bias, u16* __restrict__ Qr, u16* __restrict__ Kr,
    u16* __restrict__ Vt) {
    __shared__ __align__(16) u16 As[128 * 40];
    __shared__ __align__(16) u16 Bs[128 * 40];
    const int K = 1024;
    int tid = threadIdx.x;
    int lane = tid & 63, wave = tid >> 6;
    int col = lane & 15, quad = lane >> 4;
    int wm = wave >> 1, wn = wave & 1;
    int mBase = blockIdx.y * 128;
    int nBase = blockIdx.x * 128;
    f32x4 acc[4][4] = {};
    gemm_mainloop(A + (size_t)mBase * K, Bt + (size_t)nBase * K, K, As, Bs, tid, acc);

    int n64 = nBase + wn * 64;        // wave's 64-col span = exactly one head of q/k/v
    int region = n64 >> 10;           // 0=q, 1=k, 2=v
    int h = (n64 & 1023) >> 6;
    if (region < 2) {
        u16* out = (region == 0) ? Qr : Kr;
        const float C0 = 0.4152410118609203f;  // log2(10000)/32
#pragma unroll
        for (int nt = 0; nt < 2; ++nt) {
            int d1 = nt * 16 + col;  // 0..31, pairs with d1+32
            float inv_freq = exp2f(-C0 * (float)d1);
            float b1 = bias[n64 + nt * 16 + col];
            float b2 = bias[n64 + nt * 16 + col + 32];
#pragma unroll
            for (int mt = 0; mt < 4; ++mt) {
                int mrow = mBase + wm * 64 + mt * 16 + quad * 4;
#pragma unroll
                for (int r = 0; r < 4; ++r) {
                    int m = mrow + r;
                    int s = m & 2047, b = m >> 11;
                    float sn, cs;
                    sincosf((float)s * inv_freq, &sn, &cs);
                    float t1 = acc[mt][nt][r] + b1;
                    float t2 = acc[mt][nt + 2][r] + b2;
                    size_t base = ((size_t)((b * 16 + h) * 2048 + s)) * 64;
                    out[base + d1] = f2b(t1 * cs - t2 * sn);
                    out[base + d1 + 32] = f2b(t2 * cs + t1 * sn);
                }
            }
        }
    } else {
#pragma unroll
        for (int nt = 0; nt < 4; ++nt) {
            int d = nt * 16 + col;
            float bv = bias[n64 + nt * 16 + col];
#pragma unroll
            for (int mt = 0; mt < 4; ++mt) {
                int mrow = mBase + wm * 64 + mt * 16 + quad * 4;
#pragma unroll
                for (int r = 0; r < 4; ++r) {
                    int m = mrow + r;
                    int s = m & 2047, b = m >> 11;
                    Vt[((size_t)((b * 16 + h) * 64 + d)) * 2048 + s] =
                        f2b(acc[mt][nt][r] + bv);
                }
            }
        }
    }
}

// ---------------- flash attention (causal), 64 queries/block ----------------
// Qr,Kr: [BH][S][64] bf16 (rope'd); Vt: [BH][64][S] bf16; O: [B*S][1024] bf16
__global__ __launch_bounds__(256) void k_attn(const u16* __restrict__ Qr,
                                              const u16* __restrict__ Kr,
                                              const u16* __restrict__ Vt,
                                              u16* __restrict__ O) {
    __shared__ __align__(16) u16 Ks[64 * 72];
    __shared__ __align__(16) u16 Vs[64 * 72];
    __shared__ __align__(16) u16 Ps[4][16 * 72];
    int tid = threadIdx.x, wave = tid >> 6, lane = tid & 63;
    int col = lane & 15, quad = lane >> 4;
    int bx = blockIdx.x;  // q tile (64 queries)
    int bh = blockIdx.y;  // b*16+h
    int q0 = bx * 64;
    size_t headQ = (size_t)bh * 2048 * 64;
    size_t headV = (size_t)bh * 64 * 2048;

    // Q fragments for this wave's 16 rows (A-operand layout)
    int qrow = q0 + wave * 16 + col;
    bf16x8 aq[2];
    aq[0] = *(const bf16x8*)(Qr + headQ + (size_t)qrow * 64 + quad * 8);
    aq[1] = *(const bf16x8*)(Qr + headQ + (size_t)qrow * 64 + 32 + quad * 8);

    f32x4 o[4] = {};
    float m_old[4], l[4];
#pragma unroll
    for (int r = 0; r < 4; ++r) { m_old[r] = -3.0e38f; l[r] = 0.f; }
    int myq = q0 + wave * 16 + quad * 4;  // + r
    int r0 = tid >> 3, kc = tid & 7;
    u16* pbuf = &Ps[wave][0];

    for (int j = 0; j <= bx; ++j) {
        __syncthreads();  // previous iter's LDS reads done
#pragma unroll
        for (int it = 0; it < 2; ++it) {
            int row = r0 + it * 32;
            *(uint4*)(Ks + row * 72 + kc * 8) =
                *(const uint4*)(Kr + headQ + (size_t)(j * 64 + row) * 64 + kc * 8);
            *(uint4*)(Vs + row * 72 + kc * 8) =
                *(const uint4*)(Vt + headV + (size_t)row * 2048 + j * 64 + kc * 8);
        }
        __syncthreads();
        // S = Q K^T  (16 x 64 per wave)
        f32x4 s[4];
#pragma unroll
        for (int nt = 0; nt < 4; ++nt) {
            bf16x8 bk0 = *(const bf16x8*)(Ks + (nt * 16 + col) * 72 + quad * 8);
            bf16x8 bk1 = *(const bf16x8*)(Ks + (nt * 16 + col) * 72 + 32 + quad * 8);
            f32x4 z = {};
            z = __builtin_amdgcn_mfma_f32_16x16x32_bf16(aq[0], bk0, z, 0, 0, 0);
            s[nt] = __builtin_amdgcn_mfma_f32_16x16x32_bf16(aq[1], bk1, z, 0, 0, 0);
        }
        // online softmax
        float sv[4][4], mt_[4];
#pragma unroll
        for (int r = 0; r < 4; ++r) mt_[r] = -3.0e38f;
#pragma unroll
        for (int nt = 0; nt < 4; ++nt) {
            int key = j * 64 + nt * 16 + col;
#pragma unroll
            for (int r = 0; r < 4; ++r) {
                float v = s[nt][r] * 0.125f;
                if (key > myq + r) v = -3.0e38f;
                sv[nt][r] = v;
                mt_[r] = fmaxf(mt_[r], v);
            }
        }
#pragma unroll
        for (int off = 1; off < 16; off <<= 1)
#pragma unroll
            for (int r = 0; r < 4; ++r)
                mt_[r] = fmaxf(mt_[r], __shfl_xor(mt_[r], off));
        float m_new[4], alpha[4], rs[4];
#pragma unroll
        for (int r = 0; r < 4; ++r) {
            m_new[r] = fmaxf(m_old[r], mt_[r]);
            alpha[r] = __expf(m_old[r] - m_new[r]);
            rs[r] = 0.f;
        }
#pragma unroll
        for (int nt = 0; nt < 4; ++nt)
#pragma unroll
            for (int r = 0; r < 4; ++r) {
                float p = __expf(sv[nt][r] - m_new[r]);
                rs[r] += p;
                pbuf[(quad * 4 + r) * 72 + nt * 16 + col] = f2b(p);
            }
#pragma unroll
        for (int off = 1; off < 16; off <<= 1)
#pragma unroll
            for (int r = 0; r < 4; ++r) rs[r] += __shfl_xor(rs[r], off);
#pragma unroll
        for (int r = 0; r < 4; ++r) {
            l[r] = l[r] * alpha[r] + rs[r];
            m_old[r] = m_new[r];
        }
#pragma unroll
        for (int nt = 0; nt < 4; ++nt)
#pragma unroll
            for (int r = 0; r < 4; ++r) o[nt][r] *= alpha[r];
        __syncthreads();  // P visible (block-uniform barrier)
        // O += P @ V
#pragma unroll
        for (int kk = 0; kk < 2; ++kk) {
            bf16x8 pf = *(const bf16x8*)(pbuf + col * 72 + kk * 32 + quad * 8);
#pragma unroll
            for (int nt = 0; nt < 4; ++nt) {
                bf16x8 bv = *(const bf16x8*)(Vs + (nt * 16 + col) * 72 + kk * 32 + quad * 8);
                o[nt] = __builtin_amdgcn_mfma_f32_16x16x32_bf16(pf, bv, o[nt], 0, 0, 0);
            }
        }
    }
    int b = bh >> 4, h = bh & 15;
#pragma unroll
    for (int r = 0; r < 4; ++r) {
        float inv = 1.0f / l[r];
        int m = b * 2048 + q0 + wave * 16 + quad * 4 + r;
#pragma unroll
        for (int nt = 0; nt < 4; ++nt)
            O[(size_t)m * 1024 + h * 64 + nt * 16 + col] = f2b(o[nt][r] * inv);
    }
}

// ---------------- output projection GEMM ----------------
__global__ __launch_bounds__(256) void k_gemm_proj(const u16* __restrict__ A,
                                                   const u16* __restrict__ Bt,
                                                   const float* __restrict__ bias,
                                                   float* __restrict__ out) {
    __shared__ __align__(16) u16 As[128 * 40];
    __shared__ __align__(16) u16 Bs[128 * 40];
    const int K = 1024;
    int tid = threadIdx.x;
    int lane = tid & 63, wave = tid >> 6;
    int col = lane & 15, quad = lane >> 4;
    int wm = wave >> 1, wn = wave & 1;
    int mBase = blockIdx.y * 128;
    int nBase = blockIdx.x * 128;
    f32x4 acc[4][4] = {};
    gemm_mainloop(A + (size_t)mBase * K, Bt + (size_t)nBase * K, K, As, Bs, tid, acc);
#pragma unroll
    for (int nt = 0; nt < 4; ++nt) {
        int n = nBase + wn * 64 + nt * 16 + col;
        float bv = bias[n];
#pragma unroll
        for (int mt = 0; mt < 4; ++mt) {
            int m = mBase + wm * 64 + mt * 16 + quad * 4;
#pragma unroll
            for (int r = 0; r < 4; ++r)
                out[(size_t)(m + r) * 1024 + n] = acc[mt][nt][r] + bv;
        }
    }
}

// ---------------- launch ----------------
// workspace layout (bytes):
//   x_bf    @ 0          16,777,216   (8192x1024 bf16)
//   wqkvT   @ 16777216    6,291,456   (3072x1024 bf16)
//   wprojT  @ 23068672    2,097,152   (1024x1024 bf16)
//   Qr      @ 25165824   16,777,216   ([B,H,S,D] bf16, rope'd)
//   Kr      @ 41943040   16,777,216
//   Vt      @ 58720256   16,777,216   ([B,H,D,S] bf16)
//   AO      @ 75497472   16,777,216   (attn out, [B*S][E] bf16)
// total ~92.3 MB
extern "C" void kernel_launch(void* const* d_in, const int* in_sizes, int n_in,
                              void* d_out, int out_size, void* d_ws, size_t ws_size,
                              hipStream_t stream) {
    const float* x = (const float*)d_in[0];
    const float* w_qkv = (const float*)d_in[1];
    const float* b_qkv = (const float*)d_in[2];
    const float* w_proj = (const float*)d_in[3];
    const float* b_proj = (const float*)d_in[4];
    float* out = (float*)d_out;
    char* ws = (char*)d_ws;
    u16* x_bf = (u16*)(ws);
    u16* wqkvT = (u16*)(ws + 16777216);
    u16* wprojT = (u16*)(ws + 23068672);
    u16* Qr = (u16*)(ws + 25165824);
    u16* Kr = (u16*)(ws + 41943040);
    u16* Vt = (u16*)(ws + 58720256);
    u16* AO = (u16*)(ws + 75497472);

    k_convert<<<4096, 256, 0, stream>>>(x, x_bf, 1048576);
    k_transpose_bf16<<<dim3(48, 16), 256, 0, stream>>>(w_qkv, wqkvT, 1024, 3072);
    k_transpose_bf16<<<dim3(16, 16), 256, 0, stream>>>(w_proj, wprojT, 1024, 1024);
    k_gemm_qkv_rope<<<dim3(24, 64), 256, 0, stream>>>(x_bf, wqkvT, b_qkv, Qr, Kr, Vt);
    k_attn<<<dim3(32, 64), 256, 0, stream>>>(Qr, Kr, Vt, AO);
    k_gemm_proj<<<dim3(8, 64), 256, 0, stream>>>(AO, wprojT, b_proj, out);
}

// Round 2
// 356.182 us; speedup vs baseline: 1.2626x; 1.2626x over previous
//
#include <hip/hip_runtime.h>

typedef unsigned short u16;
typedef __bf16 bf16x8 __attribute__((ext_vector_type(8)));
typedef float f32x4 __attribute__((ext_vector_type(4)));

__device__ __forceinline__ u16 f2b(float f) {
    unsigned u = __builtin_bit_cast(unsigned, f);
    unsigned r = (u + 0x7fffu + ((u >> 16) & 1u)) >> 16;
    return (u16)r;
}
__device__ __forceinline__ unsigned pk2(float a, float b) {
    return (unsigned)f2b(a) | ((unsigned)f2b(b) << 16);
}

// ---------------- convert x (fp32 -> bf16), 8 elems/thread ----------------
__global__ __launch_bounds__(256) void k_convert(const float* __restrict__ in,
                                                 u16* __restrict__ out, int n8) {
    int i = blockIdx.x * 256 + threadIdx.x;
    if (i >= n8) return;
    const float4* p = (const float4*)(in + (size_t)i * 8);
    float4 a = p[0], b = p[1];
    u16 t[8] = {f2b(a.x), f2b(a.y), f2b(a.z), f2b(a.w),
                f2b(b.x), f2b(b.y), f2b(b.z), f2b(b.w)};
    *(uint4*)(out + (size_t)i * 8) = *(const uint4*)t;
}

// -------- transpose + convert: in[R][C] fp32 -> out[C][R] bf16, 64x64 tiles --------
__global__ __launch_bounds__(256) void k_transpose_bf16(const float* __restrict__ in,
                                                        u16* __restrict__ out,
                                                        int R, int C) {
    __shared__ u16 tile[64][72];
    int tc = blockIdx.x * 64;
    int tr = blockIdx.y * 64;
    for (int i = threadIdx.x; i < 4096; i += 256) {
        int r = i >> 6, c = i & 63;
        tile[c][r] = f2b(in[(size_t)(tr + r) * C + tc + c]);
    }
    __syncthreads();
    for (int i = threadIdx.x; i < 4096; i += 256) {
        int r = i >> 6, c = i & 63;
        out[(size_t)(tc + r) * R + tr + c] = tile[r][c];
    }
}

// ---------------- shared 128x128x(K) bf16 MFMA mainloop ----------------
__device__ __forceinline__ void gemm_mainloop(const u16* __restrict__ Ab,
                                              const u16* __restrict__ Bb, int K,
                                              u16* As, u16* Bs, int tid,
                                              f32x4 (&acc)[4][4]) {
    const int wave = tid >> 6, lane = tid & 63;
    const int col = lane & 15, quad = lane >> 4;
    const int wm = wave >> 1, wn = wave & 1;
    const int r0 = tid >> 2, kc = tid & 3;
    for (int k0 = 0; k0 < K; k0 += 32) {
        if (k0) __syncthreads();
#pragma unroll
        for (int it = 0; it < 2; ++it) {
            int row = r0 + it * 64;
            uint4 av = *(const uint4*)(Ab + (size_t)row * K + k0 + kc * 8);
            uint4 bv = *(const uint4*)(Bb + (size_t)row * K + k0 + kc * 8);
            *(uint4*)(As + row * 40 + kc * 8) = av;
            *(uint4*)(Bs + row * 40 + kc * 8) = bv;
        }
        __syncthreads();
        bf16x8 af[4], bfr[4];
#pragma unroll
        for (int mt = 0; mt < 4; ++mt)
            af[mt] = *(const bf16x8*)(As + (wm * 64 + mt * 16 + col) * 40 + quad * 8);
#pragma unroll
        for (int nt = 0; nt < 4; ++nt)
            bfr[nt] = *(const bf16x8*)(Bs + (wn * 64 + nt * 16 + col) * 40 + quad * 8);
#pragma unroll
        for (int mt = 0; mt < 4; ++mt)
#pragma unroll
            for (int nt = 0; nt < 4; ++nt)
                acc[mt][nt] = __builtin_amdgcn_mfma_f32_16x16x32_bf16(
                    af[mt], bfr[nt], acc[mt][nt], 0, 0, 0);
    }
}

// ---------------- QKV GEMM + bias + RoPE + head reshape ----------------
__global__ __launch_bounds__(256) void k_gemm_qkv_rope(
    const u16* __restrict__ A, const u16* __restrict__ Bt,
    const float* __restrict__ bias, u16* __restrict__ Qr, u16* __restrict__ Kr,
    u16* __restrict__ Vt) {
    __shared__ __align__(16) u16 As[128 * 40];
    __shared__ __align__(16) u16 Bs[128 * 40];
    const int K = 1024;
    int tid = threadIdx.x;
    int lane = tid & 63, wave = tid >> 6;
    int col = lane & 15, quad = lane >> 4;
    int wm = wave >> 1, wn = wave & 1;
    int mBase = blockIdx.y * 128;
    int nBase = blockIdx.x * 128;
    f32x4 acc[4][4] = {};
    gemm_mainloop(A + (size_t)mBase * K, Bt + (size_t)nBase * K, K, As, Bs, tid, acc);

    int n64 = nBase + wn * 64;
    int region = n64 >> 10;  // 0=q, 1=k, 2=v
    int h = (n64 & 1023) >> 6;
    if (region < 2) {
        u16* out = (region == 0) ? Qr : Kr;
        const float C0 = 0.4152410118609203f;  // log2(10000)/32
#pragma unroll
        for (int nt = 0; nt < 2; ++nt) {
            int d1 = nt * 16 + col;
            float inv_freq = exp2f(-C0 * (float)d1);
            float b1 = bias[n64 + nt * 16 + col];
            float b2 = bias[n64 + nt * 16 + col + 32];
#pragma unroll
            for (int mt = 0; mt < 4; ++mt) {
                int mrow = mBase + wm * 64 + mt * 16 + quad * 4;
#pragma unroll
                for (int r = 0; r < 4; ++r) {
                    int m = mrow + r;
                    int s = m & 2047, b = m >> 11;
                    float sn, cs;
                    sincosf((float)s * inv_freq, &sn, &cs);
                    float t1 = acc[mt][nt][r] + b1;
                    float t2 = acc[mt][nt + 2][r] + b2;
                    size_t base = ((size_t)((b * 16 + h) * 2048 + s)) * 64;
                    out[base + d1] = f2b(t1 * cs - t2 * sn);
                    out[base + d1 + 32] = f2b(t2 * cs + t1 * sn);
                }
            }
        }
    } else {
#pragma unroll
        for (int nt = 0; nt < 4; ++nt) {
            int d = nt * 16 + col;
            float bv = bias[n64 + nt * 16 + col];
#pragma unroll
            for (int mt = 0; mt < 4; ++mt) {
                int mrow = mBase + wm * 64 + mt * 16 + quad * 4;
#pragma unroll
                for (int r = 0; r < 4; ++r) {
                    int m = mrow + r;
                    int s = m & 2047, b = m >> 11;
                    Vt[((size_t)((b * 16 + h) * 64 + d)) * 2048 + s] =
                        f2b(acc[mt][nt][r] + bv);
                }
            }
        }
    }
}

// ---------------- flash attention (causal, transposed dataflow) ----------------
// Qr,Kr: [BH][S][64] bf16 (rope'd); Vt: [BH][64][S] bf16; O: [B*S][1024] bf16
// Block bx handles q-tiles {31-bx, bx} (paired => uniform 33 key-iters/block).
// Per 64-key iter: S^T = K.Q^T (C-layout: col=query, rows=keys) -> lane-scalar
// online softmax -> P^T B-frags built via shuffles (no LDS, no 3rd barrier) ->
// O^T = V.P^T. Output written transposed (lane packs 4 consecutive d per query).
__global__ __launch_bounds__(256) void k_attn(const u16* __restrict__ Qr,
                                              const u16* __restrict__ Kr,
                                              const u16* __restrict__ Vt,
                                              u16* __restrict__ O) {
    __shared__ __align__(16) u16 Ks[64 * 72];  // [key][d]
    __shared__ __align__(16) u16 Vs[64 * 72];  // [d][key]
    const float CE = 0.18033688011112042f;     // 0.125 * log2(e)
    int tid = threadIdx.x, wave = tid >> 6, lane = tid & 63;
    int col = lane & 15, quad = lane >> 4;
    int bx = blockIdx.x;
    int bh = blockIdx.y;
    int b = bh >> 4, h = bh & 15;
    size_t headQ = (size_t)bh * 2048 * 64;
    size_t headV = (size_t)bh * 64 * 2048;
    int r0 = tid >> 3, kc = tid & 7;
    int src_lo = (lane & 15) + 16 * (2 * (quad & 1));
    int src_hi = src_lo + 16;

    for (int half = 0; half < 2; ++half) {
        int qt = half ? bx : (31 - bx);
        int q0w = qt * 64 + wave * 16;
        int myq = q0w + col;
        const u16* qptr = Qr + headQ + (size_t)myq * 64;
        bf16x8 aq0 = *(const bf16x8*)(qptr + quad * 8);
        bf16x8 aq1 = *(const bf16x8*)(qptr + 32 + quad * 8);
        f32x4 o[4] = {};
        float m_old = -3.0e38f, l = 0.f;

        for (int j = 0; j <= qt; ++j) {
            __syncthreads();
#pragma unroll
            for (int it = 0; it < 2; ++it) {
                int row = r0 + it * 32;
                *(uint4*)(Ks + row * 72 + kc * 8) =
                    *(const uint4*)(Kr + headQ + (size_t)(j * 64 + row) * 64 + kc * 8);
                *(uint4*)(Vs + row * 72 + kc * 8) =
                    *(const uint4*)(Vt + headV + (size_t)row * 2048 + j * 64 + kc * 8);
            }
            __syncthreads();
            // S^T: keys (rows) x queries (cols); s[nt] covers keys nt*16..+15
            f32x4 s[4];
#pragma unroll
            for (int nt = 0; nt < 4; ++nt) {
                bf16x8 ak0 = *(const bf16x8*)(Ks + (nt * 16 + col) * 72 + quad * 8);
                bf16x8 ak1 = *(const bf16x8*)(Ks + (nt * 16 + col) * 72 + 32 + quad * 8);
                f32x4 z = {};
                z = __builtin_amdgcn_mfma_f32_16x16x32_bf16(ak0, aq0, z, 0, 0, 0);
                s[nt] = __builtin_amdgcn_mfma_f32_16x16x32_bf16(ak1, aq1, s[nt] = z, 0, 0, 0);
            }
            if (j == qt) {  // diagonal tile: causal mask (raw-score units)
#pragma unroll
                for (int nt = 0; nt < 4; ++nt)
#pragma unroll
                    for (int r = 0; r < 4; ++r) {
                        int key = j * 64 + nt * 16 + quad * 4 + r;
                        if (key > myq) s[nt][r] = -3.0e38f;
                    }
            }
            // lane-scalar online softmax (all 16 values belong to query=col)
            float mt_ = s[0][0];
#pragma unroll
            for (int nt = 0; nt < 4; ++nt)
#pragma unroll
                for (int r = 0; r < 4; ++r) mt_ = fmaxf(mt_, s[nt][r]);
            mt_ = fmaxf(mt_, __shfl_xor(mt_, 16));
            mt_ = fmaxf(mt_, __shfl_xor(mt_, 32));
            float m_new = fmaxf(m_old, mt_);
            float alpha = exp2f((m_old - m_new) * CE);
            float nmc = -m_new * CE;
            float rs = 0.f;
            unsigned P4[8];  // tile nt -> dwords P4[2nt], P4[2nt+1] (keys quad*4..+3)
#pragma unroll
            for (int nt = 0; nt < 4; ++nt) {
                float p0 = exp2f(fmaf(s[nt][0], CE, nmc));
                float p1 = exp2f(fmaf(s[nt][1], CE, nmc));
                float p2 = exp2f(fmaf(s[nt][2], CE, nmc));
                float p3 = exp2f(fmaf(s[nt][3], CE, nmc));
                rs += (p0 + p1) + (p2 + p3);
                P4[2 * nt] = pk2(p0, p1);
                P4[2 * nt + 1] = pk2(p2, p3);
            }
            rs += __shfl_xor(rs, 16);
            rs += __shfl_xor(rs, 32);
            l = l * alpha + rs;
            m_old = m_new;
#pragma unroll
            for (int mt = 0; mt < 4; ++mt) o[mt] *= alpha;
            // PV: O^T += V.P^T ; build P^T B-frag (keys kk*32+quad*8..+7) via shfl
#pragma unroll
            for (int kk = 0; kk < 2; ++kk) {
                int t0 = kk * 2, t1 = kk * 2 + 1;
                unsigned a0 = __shfl((int)P4[2 * t0], src_lo);
                unsigned a1 = __shfl((int)P4[2 * t0 + 1], src_lo);
                unsigned a2 = __shfl((int)P4[2 * t0], src_hi);
                unsigned a3 = __shfl((int)P4[2 * t0 + 1], src_hi);
                unsigned b0 = __shfl((int)P4[2 * t1], src_lo);
                unsigned b1 = __shfl((int)P4[2 * t1 + 1], src_lo);
                unsigned b2 = __shfl((int)P4[2 * t1], src_hi);
                unsigned b3 = __shfl((int)P4[2 * t1 + 1], src_hi);
                bool hi = quad >= 2;
                uint4 bpw;
                bpw.x = hi ? b0 : a0;
                bpw.y = hi ? b1 : a1;
                bpw.z = hi ? b2 : a2;
                bpw.w = hi ? b3 : a3;
                bf16x8 bp = __builtin_bit_cast(bf16x8, bpw);
#pragma unroll
                for (int mt = 0; mt < 4; ++mt) {
                    bf16x8 av = *(const bf16x8*)(Vs + (mt * 16 + col) * 72 + kk * 32 + quad * 8);
                    o[mt] = __builtin_amdgcn_mfma_f32_16x16x32_bf16(av, bp, o[mt], 0, 0, 0);
                }
            }
        }
        // epilogue: lane holds O^T[d=mt*16+quad*4+r][query=col]
        float inv = 1.0f / l;
        u16* orow = O + (size_t)(b * 2048 + myq) * 1024 + h * 64;
#pragma unroll
        for (int mt = 0; mt < 4; ++mt) {
            uint2 w;
            w.x = pk2(o[mt][0] * inv, o[mt][1] * inv);
            w.y = pk2(o[mt][2] * inv, o[mt][3] * inv);
            *(uint2*)(orow + mt * 16 + quad * 4) = w;
        }
    }
}

// ---------------- output projection GEMM ----------------
__global__ __launch_bounds__(256) void k_gemm_proj(const u16* __restrict__ A,
                                                   const u16* __restrict__ Bt,
                                                   const float* __restrict__ bias,
                                                   float* __restrict__ out) {
    __shared__ __align__(16) u16 As[128 * 40];
    __shared__ __align__(16) u16 Bs[128 * 40];
    const int K = 1024;
    int tid = threadIdx.x;
    int lane = tid & 63, wave = tid >> 6;
    int col = lane & 15, quad = lane >> 4;
    int wm = wave >> 1, wn = wave & 1;
    int mBase = blockIdx.y * 128;
    int nBase = blockIdx.x * 128;
    f32x4 acc[4][4] = {};
    gemm_mainloop(A + (size_t)mBase * K, Bt + (size_t)nBase * K, K, As, Bs, tid, acc);
#pragma unroll
    for (int nt = 0; nt < 4; ++nt) {
        int n = nBase + wn * 64 + nt * 16 + col;
        float bv = bias[n];
#pragma unroll
        for (int mt = 0; mt < 4; ++mt) {
            int m = mBase + wm * 64 + mt * 16 + quad * 4;
#pragma unroll
            for (int r = 0; r < 4; ++r)
                out[(size_t)(m + r) * 1024 + n] = acc[mt][nt][r] + bv;
        }
    }
}

// ---------------- launch ----------------
// workspace layout (bytes):
//   x_bf    @ 0          16,777,216   (8192x1024 bf16)
//   wqkvT   @ 16777216    6,291,456   (3072x1024 bf16)
//   wprojT  @ 23068672    2,097,152   (1024x1024 bf16)
//   Qr      @ 25165824   16,777,216   ([B,H,S,D] bf16, rope'd)
//   Kr      @ 41943040   16,777,216
//   Vt      @ 58720256   16,777,216   ([B,H,D,S] bf16)
//   AO      @ 75497472   16,777,216   (attn out, [B*S][E] bf16)
extern "C" void kernel_launch(void* const* d_in, const int* in_sizes, int n_in,
                              void* d_out, int out_size, void* d_ws, size_t ws_size,
                              hipStream_t stream) {
    const float* x = (const float*)d_in[0];
    const float* w_qkv = (const float*)d_in[1];
    const float* b_qkv = (const float*)d_in[2];
    const float* w_proj = (const float*)d_in[3];
    const float* b_proj = (const float*)d_in[4];
    float* out = (float*)d_out;
    char* ws = (char*)d_ws;
    u16* x_bf = (u16*)(ws);
    u16* wqkvT = (u16*)(ws + 16777216);
    u16* wprojT = (u16*)(ws + 23068672);
    u16* Qr = (u16*)(ws + 25165824);
    u16* Kr = (u16*)(ws + 41943040);
    u16* Vt = (u16*)(ws + 58720256);
    u16* AO = (u16*)(ws + 75497472);

    k_convert<<<4096, 256, 0, stream>>>(x, x_bf, 1048576);
    k_transpose_bf16<<<dim3(48, 16), 256, 0, stream>>>(w_qkv, wqkvT, 1024, 3072);
    k_transpose_bf16<<<dim3(16, 16), 256, 0, stream>>>(w_proj, wprojT, 1024, 1024);
    k_gemm_qkv_rope<<<dim3(24, 64), 256, 0, stream>>>(x_bf, wqkvT, b_qkv, Qr, Kr, Vt);
    k_attn<<<dim3(16, 64), 256, 0, stream>>>(Qr, Kr, Vt, AO);
    k_gemm_proj<<<dim3(8, 64), 256, 0, stream>>>(AO, wprojT, b_proj, out);
}

// Round 4
// 299.122 us; speedup vs baseline: 1.5034x; 1.1908x over previous
//
#include <hip/hip_runtime.h>

typedef unsigned short u16;
typedef __bf16 bf16x8 __attribute__((ext_vector_type(8)));
typedef float f32x4 __attribute__((ext_vector_type(4)));

__device__ __forceinline__ u16 f2b(float f) {
    unsigned u = __builtin_bit_cast(unsigned, f);
    unsigned r = (u + 0x7fffu + ((u >> 16) & 1u)) >> 16;
    return (u16)r;
}
#if __has_builtin(__builtin_amdgcn_cvt_pk_bf16_f32)
typedef __bf16 bf16x2_t __attribute__((ext_vector_type(2)));
__device__ __forceinline__ unsigned pk2(float a, float b) {
    return __builtin_bit_cast(unsigned, __builtin_amdgcn_cvt_pk_bf16_f32(a, b));
}
#else
__device__ __forceinline__ unsigned pk2(float a, float b) {
    return (unsigned)f2b(a) | ((unsigned)f2b(b) << 16);
}
#endif
#if __has_builtin(__builtin_amdgcn_exp2f)
#define EXP2F(x) __builtin_amdgcn_exp2f(x)
#else
#define EXP2F(x) exp2f(x)
#endif

// async global->LDS 16B/lane; lds dest is wave-uniform base (+lane*16 by HW)
__device__ __forceinline__ void gl_lds16(const u16* g, u16* l) {
    __builtin_amdgcn_global_load_lds(
        (const __attribute__((address_space(1))) unsigned*)(const void*)g,
        (__attribute__((address_space(3))) unsigned*)(void*)l, 16, 0, 0);
}

// ---------------- convert x (fp32 -> bf16), 8 elems/thread ----------------
__global__ __launch_bounds__(256) void k_convert(const float* __restrict__ in,
                                                 u16* __restrict__ out, int n8) {
    int i = blockIdx.x * 256 + threadIdx.x;
    if (i >= n8) return;
    const float4* p = (const float4*)(in + (size_t)i * 8);
    float4 a = p[0], b = p[1];
    u16 t[8] = {f2b(a.x), f2b(a.y), f2b(a.z), f2b(a.w),
                f2b(b.x), f2b(b.y), f2b(b.z), f2b(b.w)};
    *(uint4*)(out + (size_t)i * 8) = *(const uint4*)t;
}

// -------- transpose + convert: in[R][C] fp32 -> out[C][R] bf16, 64x64 tiles --------
__global__ __launch_bounds__(256) void k_transpose_bf16(const float* __restrict__ in,
                                                        u16* __restrict__ out,
                                                        int R, int C) {
    __shared__ u16 tile[64][72];
    int tc = blockIdx.x * 64;
    int tr = blockIdx.y * 64;
    for (int i = threadIdx.x; i < 4096; i += 256) {
        int r = i >> 6, c = i & 63;
        tile[c][r] = f2b(in[(size_t)(tr + r) * C + tc + c]);
    }
    __syncthreads();
    for (int i = threadIdx.x; i < 4096; i += 256) {
        int r = i >> 6, c = i & 63;
        out[(size_t)(tc + r) * R + tr + c] = tile[r][c];
    }
}

// ------- 128x128x(K) bf16 MFMA mainloop, global_load_lds staging (m97-style) -------
// LDS tiles 128x32 bf16 UNPADDED (lane-order contiguous for the DMA deposit):
// lane i of wave w deposits global row w*16+(i>>2), cols (i&3)*8..+7 at byte
// offset w*2048 + 16*i == row-major [128][32] u16. Frag reads are b128.
__device__ __forceinline__ void gemm_mainloop(const u16* __restrict__ Ab,
                                              const u16* __restrict__ Bb, int K,
                                              u16* As, u16* Bs, int tid,
                                              f32x4 (&acc)[4][4]) {
    const int wave = tid >> 6, lane = tid & 63;
    const int col = lane & 15, quad = lane >> 4;
    const int wm = wave >> 1, wn = wave & 1;
    const int lrow = lane >> 2, lk = (lane & 3) * 8;
    u16* ldsA0 = As + (wave * 16) * 32;  // wave-uniform segment bases
    u16* ldsA1 = As + (64 + wave * 16) * 32;
    u16* ldsB0 = Bs + (wave * 16) * 32;
    u16* ldsB1 = Bs + (64 + wave * 16) * 32;
    const u16* gA0 = Ab + (size_t)(wave * 16 + lrow) * K + lk;
    const u16* gA1 = gA0 + (size_t)64 * K;
    const u16* gB0 = Bb + (size_t)(wave * 16 + lrow) * K + lk;
    const u16* gB1 = gB0 + (size_t)64 * K;
    for (int k0 = 0; k0 < K; k0 += 32) {
        if (k0) __syncthreads();
        gl_lds16(gA0 + k0, ldsA0);
        gl_lds16(gA1 + k0, ldsA1);
        gl_lds16(gB0 + k0, ldsB0);
        gl_lds16(gB1 + k0, ldsB1);
        __syncthreads();  // compiler drains vmcnt(0) before s_barrier
        bf16x8 af[4], bfr[4];
#pragma unroll
        for (int mt = 0; mt < 4; ++mt)
            af[mt] = *(const bf16x8*)(As + (wm * 64 + mt * 16 + col) * 32 + quad * 8);
#pragma unroll
        for (int nt = 0; nt < 4; ++nt)
            bfr[nt] = *(const bf16x8*)(Bs + (wn * 64 + nt * 16 + col) * 32 + quad * 8);
#pragma unroll
        for (int mt = 0; mt < 4; ++mt)
#pragma unroll
            for (int nt = 0; nt < 4; ++nt)
                acc[mt][nt] = __builtin_amdgcn_mfma_f32_16x16x32_bf16(
                    af[mt], bfr[nt], acc[mt][nt], 0, 0, 0);
    }
}

// ---------------- QKV GEMM + bias + RoPE + head reshape ----------------
// Q additionally prescaled by 0.125*log2(e) so attention softmax is pure exp2.
__global__ __launch_bounds__(256) void k_gemm_qkv_rope(
    const u16* __restrict__ A, const u16* __restrict__ Bt,
    const float* __restrict__ bias, u16* __restrict__ Qr, u16* __restrict__ Kr,
    u16* __restrict__ Vt) {
    __shared__ __align__(16) u16 As[128 * 32];
    __shared__ __align__(16) u16 Bs[128 * 32];
    const int K = 1024;
    int tid = threadIdx.x;
    int lane = tid & 63, wave = tid >> 6;
    int col = lane & 15, quad = lane >> 4;
    int wm = wave >> 1, wn = wave & 1;
    int mBase = blockIdx.y * 128;
    int nBase = blockIdx.x * 128;
    f32x4 acc[4][4] = {};
    gemm_mainloop(A + (size_t)mBase * K, Bt + (size_t)nBase * K, K, As, Bs, tid, acc);

    int n64 = nBase + wn * 64;
    int region = n64 >> 10;  // 0=q, 1=k, 2=v
    int h = (n64 & 1023) >> 6;
    if (region < 2) {
        u16* out = (region == 0) ? Qr : Kr;
        float qs = (region == 0) ? 0.18033688011112042f : 1.0f;  // 0.125*log2(e)
        const float C0 = 0.4152410118609203f;                    // log2(10000)/32
#pragma unroll
        for (int nt = 0; nt < 2; ++nt) {
            int d1 = nt * 16 + col;
            float inv_freq = exp2f(-C0 * (float)d1);
            float b1 = bias[n64 + nt * 16 + col];
            float b2 = bias[n64 + nt * 16 + col + 32];
#pragma unroll
            for (int mt = 0; mt < 4; ++mt) {
                int mrow = mBase + wm * 64 + mt * 16 + quad * 4;
#pragma unroll
                for (int r = 0; r < 4; ++r) {
                    int m = mrow + r;
                    int s = m & 2047, b = m >> 11;
                    float sn, cs;
                    sincosf((float)s * inv_freq, &sn, &cs);
                    float t1 = acc[mt][nt][r] + b1;
                    float t2 = acc[mt][nt + 2][r] + b2;
                    size_t base = ((size_t)((b * 16 + h) * 2048 + s)) * 64;
                    out[base + d1] = f2b((t1 * cs - t2 * sn) * qs);
                    out[base + d1 + 32] = f2b((t2 * cs + t1 * sn) * qs);
                }
            }
        }
    } else {
#pragma unroll
        for (int nt = 0; nt < 4; ++nt) {
            int d = nt * 16 + col;
            float bv = bias[n64 + nt * 16 + col];
#pragma unroll
            for (int mt = 0; mt < 4; ++mt) {
                int mrow = mBase + wm * 64 + mt * 16 + quad * 4;
#pragma unroll
                for (int r = 0; r < 4; ++r) {
                    int m = mrow + r;
                    int s = m & 2047, b = m >> 11;
                    Vt[((size_t)((b * 16 + h) * 64 + d)) * 2048 + s] =
                        f2b(acc[mt][nt][r] + bv);
                }
            }
        }
    }
}

// ---------------- flash attention (causal, transposed, permuted-row) ----------------
// S^T = K.Q^T with A-rows permuted: tile nt reads Ks row g(nt,col) =
// (nt&1)*32 + (col>>2)*8 + (nt>>1)*4 + (col&3). Then lane (col,quad) reg (nt,r)
// holds key (nt&1)*32 + quad*8 + (nt>>1)*4 + r  =>  PV B-frag is LANE-LOCAL
// (no shuffles): bpw(kk) = {P4[2kk],P4[2kk+1],P4[2kk+4],P4[2kk+5]}.
// Fixed-max softmax (Q prescaled by 0.125*log2e; raw |score| <~ 20 => exp2 safe).
// LDS row stride 72 u16 (rows hold 64 elems + 8 pad; 144B = 16B-aligned).
__global__ __launch_bounds__(256) void k_attn(const u16* __restrict__ Qr,
                                              const u16* __restrict__ Kr,
                                              const u16* __restrict__ Vt,
                                              u16* __restrict__ O) {
    __shared__ __align__(16) u16 Ks[64 * 72];  // [key][d]
    __shared__ __align__(16) u16 Vs[64 * 72];  // [d][key]
    int tid = threadIdx.x, wave = tid >> 6, lane = tid & 63;
    int col = lane & 15, quad = lane >> 4;
    int bx = blockIdx.x, bh = blockIdx.y;
    int b = bh >> 4, h = bh & 15;
    size_t headQ = (size_t)bh * 2048 * 64;
    size_t headV = (size_t)bh * 64 * 2048;
    int r0 = tid >> 3, kc = tid & 7;
    int rb72 = ((col >> 2) * 8 + (col & 3)) * 72;  // permuted row base

    for (int half = 0; half < 2; ++half) {
        int qt = half ? bx : (31 - bx);
        int myq = qt * 64 + wave * 16 + col;
        const u16* qptr = Qr + headQ + (size_t)myq * 64;
        bf16x8 aq0 = *(const bf16x8*)(qptr + quad * 8);
        bf16x8 aq1 = *(const bf16x8*)(qptr + 32 + quad * 8);
        f32x4 o[4] = {};
        float l = 0.f;

        for (int j = 0; j <= qt; ++j) {
            __syncthreads();
            {
                const u16* kg = Kr + headQ + (size_t)(j * 64 + r0) * 64 + kc * 8;
                const u16* vg = Vt + headV + (size_t)r0 * 2048 + j * 64 + kc * 8;
                *(uint4*)(Ks + r0 * 72 + kc * 8) = *(const uint4*)kg;
                *(uint4*)(Ks + (r0 + 32) * 72 + kc * 8) = *(const uint4*)(kg + 32 * 64);
                *(uint4*)(Vs + r0 * 72 + kc * 8) = *(const uint4*)vg;
                *(uint4*)(Vs + (r0 + 32) * 72 + kc * 8) = *(const uint4*)(vg + 32 * 2048);
            }
            __syncthreads();
            f32x4 s[4];
#pragma unroll
            for (int nt = 0; nt < 4; ++nt) {
                const u16* kp = Ks + rb72 + ((nt & 1) * 32 + (nt >> 1) * 4) * 72;
                bf16x8 ak0 = *(const bf16x8*)(kp + quad * 8);
                bf16x8 ak1 = *(const bf16x8*)(kp + 32 + quad * 8);
                f32x4 z = {};
                z = __builtin_amdgcn_mfma_f32_16x16x32_bf16(ak0, aq0, z, 0, 0, 0);
                s[nt] = __builtin_amdgcn_mfma_f32_16x16x32_bf16(ak1, aq1, z, 0, 0, 0);
            }
            if (j == qt) {  // diagonal: causal mask under the permuted key map
#pragma unroll
                for (int nt = 0; nt < 4; ++nt) {
                    int keyb = qt * 64 + (nt & 1) * 32 + quad * 8 + (nt >> 1) * 4;
#pragma unroll
                    for (int r = 0; r < 4; ++r)
                        if (keyb + r > myq) s[nt][r] = -3.0e38f;
                }
            }
            unsigned P4[8];
#pragma unroll
            for (int nt = 0; nt < 4; ++nt) {
                float p0 = EXP2F(s[nt][0]);
                float p1 = EXP2F(s[nt][1]);
                float p2 = EXP2F(s[nt][2]);
                float p3 = EXP2F(s[nt][3]);
                l += (p0 + p1) + (p2 + p3);
                P4[2 * nt] = pk2(p0, p1);
                P4[2 * nt + 1] = pk2(p2, p3);
            }
#pragma unroll
            for (int kk = 0; kk < 2; ++kk) {
                uint4 bw;
                bw.x = P4[2 * kk];
                bw.y = P4[2 * kk + 1];
                bw.z = P4[2 * kk + 4];
                bw.w = P4[2 * kk + 5];
                bf16x8 bp = __builtin_bit_cast(bf16x8, bw);
#pragma unroll
                for (int mt = 0; mt < 4; ++mt) {
                    bf16x8 av = *(const bf16x8*)(Vs + (mt * 16 + col) * 72 + kk * 32 + quad * 8);
                    o[mt] = __builtin_amdgcn_mfma_f32_16x16x32_bf16(av, bp, o[mt], 0, 0, 0);
                }
            }
        }
        l += __shfl_xor(l, 16);
        l += __shfl_xor(l, 32);
        float inv = 1.0f / l;
        u16* orow = O + (size_t)(b * 2048 + myq) * 1024 + h * 64;
#pragma unroll
        for (int mt = 0; mt < 4; ++mt) {
            uint2 w;
            w.x = pk2(o[mt][0] * inv, o[mt][1] * inv);
            w.y = pk2(o[mt][2] * inv, o[mt][3] * inv);
            *(uint2*)(orow + mt * 16 + quad * 4) = w;
        }
    }
}

// ---------------- output projection GEMM ----------------
__global__ __launch_bounds__(256) void k_gemm_proj(const u16* __restrict__ A,
                                                   const u16* __restrict__ Bt,
                                                   const float* __restrict__ bias,
                                                   float* __restrict__ out) {
    __shared__ __align__(16) u16 As[128 * 32];
    __shared__ __align__(16) u16 Bs[128 * 32];
    const int K = 1024;
    int tid = threadIdx.x;
    int lane = tid & 63, wave = tid >> 6;
    int col = lane & 15, quad = lane >> 4;
    int wm = wave >> 1, wn = wave & 1;
    int mBase = blockIdx.y * 128;
    int nBase = blockIdx.x * 128;
    f32x4 acc[4][4] = {};
    gemm_mainloop(A + (size_t)mBase * K, Bt + (size_t)nBase * K, K, As, Bs, tid, acc);
#pragma unroll
    for (int nt = 0; nt < 4; ++nt) {
        int n = nBase + wn * 64 + nt * 16 + col;
        float bv = bias[n];
#pragma unroll
        for (int mt = 0; mt < 4; ++mt) {
            int m = mBase + wm * 64 + mt * 16 + quad * 4;
#pragma unroll
            for (int r = 0; r < 4; ++r)
                out[(size_t)(m + r) * 1024 + n] = acc[mt][nt][r] + bv;
        }
    }
}

// ---------------- launch ----------------
// ws: x_bf@0 (16MB) wqkvT (6MB) wprojT (2MB) Qr Kr Vt AO (16MB each)
extern "C" void kernel_launch(void* const* d_in, const int* in_sizes, int n_in,
                              void* d_out, int out_size, void* d_ws, size_t ws_size,
                              hipStream_t stream) {
    const float* x = (const float*)d_in[0];
    const float* w_qkv = (const float*)d_in[1];
    const float* b_qkv = (const float*)d_in[2];
    const float* w_proj = (const float*)d_in[3];
    const float* b_proj = (const float*)d_in[4];
    float* out = (float*)d_out;
    char* ws = (char*)d_ws;
    u16* x_bf = (u16*)(ws);
    u16* wqkvT = (u16*)(ws + 16777216);
    u16* wprojT = (u16*)(ws + 23068672);
    u16* Qr = (u16*)(ws + 25165824);
    u16* Kr = (u16*)(ws + 41943040);
    u16* Vt = (u16*)(ws + 58720256);
    u16* AO = (u16*)(ws + 75497472);

    k_convert<<<4096, 256, 0, stream>>>(x, x_bf, 1048576);
    k_transpose_bf16<<<dim3(48, 16), 256, 0, stream>>>(w_qkv, wqkvT, 1024, 3072);
    k_transpose_bf16<<<dim3(16, 16), 256, 0, stream>>>(w_proj, wprojT, 1024, 1024);
    k_gemm_qkv_rope<<<dim3(24, 64), 256, 0, stream>>>(x_bf, wqkvT, b_qkv, Qr, Kr, Vt);
    k_attn<<<dim3(16, 64), 256, 0, stream>>>(Qr, Kr, Vt, AO);
    k_gemm_proj<<<dim3(8, 64), 256, 0, stream>>>(AO, wprojT, b_proj, out);
}

// Round 5
// 278.064 us; speedup vs baseline: 1.6173x; 1.0757x over previous
//
#include <hip/hip_runtime.h>

typedef unsigned short u16;
typedef __bf16 bf16x8 __attribute__((ext_vector_type(8)));
typedef float f32x4 __attribute__((ext_vector_type(4)));

__device__ __forceinline__ u16 f2b(float f) {
    unsigned u = __builtin_bit_cast(unsigned, f);
    unsigned r = (u + 0x7fffu + ((u >> 16) & 1u)) >> 16;
    return (u16)r;
}
#if __has_builtin(__builtin_amdgcn_cvt_pk_bf16_f32)
typedef __bf16 bf16x2_t __attribute__((ext_vector_type(2)));
__device__ __forceinline__ unsigned pk2(float a, float b) {
    return __builtin_bit_cast(unsigned, __builtin_amdgcn_cvt_pk_bf16_f32(a, b));
}
#else
__device__ __forceinline__ unsigned pk2(float a, float b) {
    return (unsigned)f2b(a) | ((unsigned)f2b(b) << 16);
}
#endif
#if __has_builtin(__builtin_amdgcn_exp2f)
#define EXP2F(x) __builtin_amdgcn_exp2f(x)
#else
#define EXP2F(x) exp2f(x)
#endif

// async global->LDS 16B/lane; lds dest is wave-uniform base (+lane*16 by HW)
__device__ __forceinline__ void gl_lds16(const u16* g, u16* l) {
    __builtin_amdgcn_global_load_lds(
        (const __attribute__((address_space(1))) unsigned*)(const void*)g,
        (__attribute__((address_space(3))) unsigned*)(void*)l, 16, 0, 0);
}

// ---------------- convert x (fp32 -> bf16), 8 elems/thread ----------------
__global__ __launch_bounds__(256) void k_convert(const float* __restrict__ in,
                                                 u16* __restrict__ out, int n8) {
    int i = blockIdx.x * 256 + threadIdx.x;
    if (i >= n8) return;
    const float4* p = (const float4*)(in + (size_t)i * 8);
    float4 a = p[0], b = p[1];
    u16 t[8] = {f2b(a.x), f2b(a.y), f2b(a.z), f2b(a.w),
                f2b(b.x), f2b(b.y), f2b(b.z), f2b(b.w)};
    *(uint4*)(out + (size_t)i * 8) = *(const uint4*)t;
}

// -------- transpose + convert: in[R][C] fp32 -> out[C][R] bf16, 64x64 tiles --------
__global__ __launch_bounds__(256) void k_transpose_bf16(const float* __restrict__ in,
                                                        u16* __restrict__ out,
                                                        int R, int C) {
    __shared__ u16 tile[64][72];
    int tc = blockIdx.x * 64;
    int tr = blockIdx.y * 64;
    for (int i = threadIdx.x; i < 4096; i += 256) {
        int r = i >> 6, c = i & 63;
        tile[c][r] = f2b(in[(size_t)(tr + r) * C + tc + c]);
    }
    __syncthreads();
    for (int i = threadIdx.x; i < 4096; i += 256) {
        int r = i >> 6, c = i & 63;
        out[(size_t)(tc + r) * R + tr + c] = tile[r][c];
    }
}

// ------- 128x128xK bf16 MFMA mainloop, BK=64 (2x32 stages per barrier pair) -------
// LDS: two 128x32 subtiles per operand (32 KB total), unpadded for DMA deposit.
// Barrier count halved vs BK=32: the vmcnt(0)+s_barrier drain amortizes over
// 32 MFMA instead of 16.
__device__ __forceinline__ void gemm_mainloop(const u16* __restrict__ Ab,
                                              const u16* __restrict__ Bb, int K,
                                              u16* As, u16* Bs, int tid,
                                              f32x4 (&acc)[4][4]) {
    const int wave = tid >> 6, lane = tid & 63;
    const int col = lane & 15, quad = lane >> 4;
    const int wm = wave >> 1, wn = wave & 1;
    const int lrow = lane >> 2, lk = (lane & 3) * 8;
    u16* ldsA0 = As + (wave * 16) * 32;  // wave-uniform segment bases
    u16* ldsA1 = As + (64 + wave * 16) * 32;
    u16* ldsB0 = Bs + (wave * 16) * 32;
    u16* ldsB1 = Bs + (64 + wave * 16) * 32;
    const u16* gA0 = Ab + (size_t)(wave * 16 + lrow) * K + lk;
    const u16* gA1 = gA0 + (size_t)64 * K;
    const u16* gB0 = Bb + (size_t)(wave * 16 + lrow) * K + lk;
    const u16* gB1 = gB0 + (size_t)64 * K;
    for (int k0 = 0; k0 < K; k0 += 64) {
        if (k0) __syncthreads();
#pragma unroll
        for (int kh = 0; kh < 2; ++kh) {
            int ko = k0 + kh * 32;
            gl_lds16(gA0 + ko, ldsA0 + kh * 4096);
            gl_lds16(gA1 + ko, ldsA1 + kh * 4096);
            gl_lds16(gB0 + ko, ldsB0 + kh * 4096);
            gl_lds16(gB1 + ko, ldsB1 + kh * 4096);
        }
        __syncthreads();  // compiler drains vmcnt(0) before s_barrier
#pragma unroll
        for (int kh = 0; kh < 2; ++kh) {
            bf16x8 af[4], bfr[4];
#pragma unroll
            for (int mt = 0; mt < 4; ++mt)
                af[mt] = *(const bf16x8*)(As + kh * 4096 +
                                          (wm * 64 + mt * 16 + col) * 32 + quad * 8);
#pragma unroll
            for (int nt = 0; nt < 4; ++nt)
                bfr[nt] = *(const bf16x8*)(Bs + kh * 4096 +
                                           (wn * 64 + nt * 16 + col) * 32 + quad * 8);
#pragma unroll
            for (int mt = 0; mt < 4; ++mt)
#pragma unroll
                for (int nt = 0; nt < 4; ++nt)
                    acc[mt][nt] = __builtin_amdgcn_mfma_f32_16x16x32_bf16(
                        af[mt], bfr[nt], acc[mt][nt], 0, 0, 0);
        }
    }
}

// ---------------- QKV GEMM + bias + RoPE + head reshape ----------------
// Q additionally prescaled by 0.125*log2(e) so attention softmax is pure exp2.
__global__ __launch_bounds__(256) void k_gemm_qkv_rope(
    const u16* __restrict__ A, const u16* __restrict__ Bt,
    const float* __restrict__ bias, u16* __restrict__ Qr, u16* __restrict__ Kr,
    u16* __restrict__ Vt) {
    __shared__ __align__(16) u16 As[2 * 128 * 32];
    __shared__ __align__(16) u16 Bs[2 * 128 * 32];
    const int K = 1024;
    int tid = threadIdx.x;
    int lane = tid & 63, wave = tid >> 6;
    int col = lane & 15, quad = lane >> 4;
    int wm = wave >> 1, wn = wave & 1;
    int mBase = blockIdx.y * 128;
    int nBase = blockIdx.x * 128;
    f32x4 acc[4][4] = {};
    gemm_mainloop(A + (size_t)mBase * K, Bt + (size_t)nBase * K, K, As, Bs, tid, acc);

    int n64 = nBase + wn * 64;
    int region = n64 >> 10;  // 0=q, 1=k, 2=v
    int h = (n64 & 1023) >> 6;
    if (region < 2) {
        u16* out = (region == 0) ? Qr : Kr;
        float qs = (region == 0) ? 0.18033688011112042f : 1.0f;  // 0.125*log2(e)
        const float C0 = 0.4152410118609203f;                    // log2(10000)/32
#pragma unroll
        for (int nt = 0; nt < 2; ++nt) {
            int d1 = nt * 16 + col;
            float inv_freq = exp2f(-C0 * (float)d1);
            float b1 = bias[n64 + nt * 16 + col];
            float b2 = bias[n64 + nt * 16 + col + 32];
#pragma unroll
            for (int mt = 0; mt < 4; ++mt) {
                int mrow = mBase + wm * 64 + mt * 16 + quad * 4;
#pragma unroll
                for (int r = 0; r < 4; ++r) {
                    int m = mrow + r;
                    int s = m & 2047, b = m >> 11;
                    float sn, cs;
                    sincosf((float)s * inv_freq, &sn, &cs);
                    float t1 = acc[mt][nt][r] + b1;
                    float t2 = acc[mt][nt + 2][r] + b2;
                    size_t base = ((size_t)((b * 16 + h) * 2048 + s)) * 64;
                    out[base + d1] = f2b((t1 * cs - t2 * sn) * qs);
                    out[base + d1 + 32] = f2b((t2 * cs + t1 * sn) * qs);
                }
            }
        }
    } else {
#pragma unroll
        for (int nt = 0; nt < 4; ++nt) {
            int d = nt * 16 + col;
            float bv = bias[n64 + nt * 16 + col];
#pragma unroll
            for (int mt = 0; mt < 4; ++mt) {
                int mrow = mBase + wm * 64 + mt * 16 + quad * 4;
#pragma unroll
                for (int r = 0; r < 4; ++r) {
                    int m = mrow + r;
                    int s = m & 2047, b = m >> 11;
                    Vt[((size_t)((b * 16 + h) * 64 + d)) * 2048 + s] =
                        f2b(acc[mt][nt][r] + bv);
                }
            }
        }
    }
}

// ------------- flash attention (causal, transposed, permuted-row, 128q/block) -------------
// Block covers 128 queries = two 64-q tiles t0=2qb, t1=2qb+1; wave owns 16-q
// subtiles at q=qb*128+w*16 (sub0, tile t0) and +64 (sub1, tile t1). K/V frags
// are read from LDS ONCE per iter and reused by both subtiles (halves per-query
// LDS traffic vs 64q blocks). Key-tile loop j=0..t1; sub0 masked at j==t0,
// inactive at j==t1; sub1 masked at j==t1. qb paired bx<->15-bx: uniform 34 iters.
// Permuted-row QK^T: tile nt reads Ks row (nt&1)*32+(col>>2)*8+(nt>>1)*4+(col&3)
// so lane reg (nt,r) holds key (nt&1)*32+quad*8+(nt>>1)*4+r => PV B-frag is
// lane-local: {P4[2kk],P4[2kk+1],P4[2kk+4],P4[2kk+5]}. Fixed-max softmax.
__global__ __launch_bounds__(256) void k_attn(const u16* __restrict__ Qr,
                                              const u16* __restrict__ Kr,
                                              const u16* __restrict__ Vt,
                                              u16* __restrict__ O) {
    __shared__ __align__(16) u16 Ks[64 * 72];  // [key][d]
    __shared__ __align__(16) u16 Vs[64 * 72];  // [d][key]
    int tid = threadIdx.x, wave = tid >> 6, lane = tid & 63;
    int col = lane & 15, quad = lane >> 4;
    int bx = blockIdx.x, bh = blockIdx.y;
    int b = bh >> 4, h = bh & 15;
    size_t headQ = (size_t)bh * 2048 * 64;
    size_t headV = (size_t)bh * 64 * 2048;
    int r0 = tid >> 3, kc = tid & 7;
    int rb72 = ((col >> 2) * 8 + (col & 3)) * 72;  // permuted row base

    for (int half = 0; half < 2; ++half) {
        int qb = half ? bx : (15 - bx);
        int t0 = 2 * qb, t1 = t0 + 1;
        int myq0 = qb * 128 + wave * 16 + col;
        int myq1 = myq0 + 64;
        const u16* qp0 = Qr + headQ + (size_t)myq0 * 64;
        const u16* qp1 = Qr + headQ + (size_t)myq1 * 64;
        bf16x8 aq00 = *(const bf16x8*)(qp0 + quad * 8);
        bf16x8 aq01 = *(const bf16x8*)(qp0 + 32 + quad * 8);
        bf16x8 aq10 = *(const bf16x8*)(qp1 + quad * 8);
        bf16x8 aq11 = *(const bf16x8*)(qp1 + 32 + quad * 8);
        f32x4 o0[4] = {}, o1[4] = {};
        float l0 = 0.f, l1 = 0.f;

        for (int j = 0; j <= t1; ++j) {
            bool d0 = (j <= t0);  // block-uniform
            __syncthreads();
            {
                const u16* kg = Kr + headQ + (size_t)(j * 64 + r0) * 64 + kc * 8;
                const u16* vg = Vt + headV + (size_t)r0 * 2048 + j * 64 + kc * 8;
                *(uint4*)(Ks + r0 * 72 + kc * 8) = *(const uint4*)kg;
                *(uint4*)(Ks + (r0 + 32) * 72 + kc * 8) = *(const uint4*)(kg + 32 * 64);
                *(uint4*)(Vs + r0 * 72 + kc * 8) = *(const uint4*)vg;
                *(uint4*)(Vs + (r0 + 32) * 72 + kc * 8) = *(const uint4*)(vg + 32 * 2048);
            }
            __syncthreads();
            f32x4 s0[4], s1[4];
#pragma unroll
            for (int nt = 0; nt < 4; ++nt) {
                const u16* kp = Ks + rb72 + ((nt & 1) * 32 + (nt >> 1) * 4) * 72;
                bf16x8 ak0 = *(const bf16x8*)(kp + quad * 8);
                bf16x8 ak1 = *(const bf16x8*)(kp + 32 + quad * 8);
                if (d0) {
                    f32x4 z = {};
                    z = __builtin_amdgcn_mfma_f32_16x16x32_bf16(ak0, aq00, z, 0, 0, 0);
                    s0[nt] = __builtin_amdgcn_mfma_f32_16x16x32_bf16(ak1, aq01, z, 0, 0, 0);
                }
                f32x4 z = {};
                z = __builtin_amdgcn_mfma_f32_16x16x32_bf16(ak0, aq10, z, 0, 0, 0);
                s1[nt] = __builtin_amdgcn_mfma_f32_16x16x32_bf16(ak1, aq11, z, 0, 0, 0);
            }
            if (j == t0) {  // diagonal for sub0
#pragma unroll
                for (int nt = 0; nt < 4; ++nt) {
                    int keyb = j * 64 + (nt & 1) * 32 + quad * 8 + (nt >> 1) * 4;
#pragma unroll
                    for (int r = 0; r < 4; ++r)
                        if (keyb + r > myq0) s0[nt][r] = -3.0e38f;
                }
            }
            if (j == t1) {  // diagonal for sub1
#pragma unroll
                for (int nt = 0; nt < 4; ++nt) {
                    int keyb = j * 64 + (nt & 1) * 32 + quad * 8 + (nt >> 1) * 4;
#pragma unroll
                    for (int r = 0; r < 4; ++r)
                        if (keyb + r > myq1) s1[nt][r] = -3.0e38f;
                }
            }
            unsigned P40[8], P41[8];
            if (d0) {
#pragma unroll
                for (int nt = 0; nt < 4; ++nt) {
                    float p0 = EXP2F(s0[nt][0]);
                    float p1 = EXP2F(s0[nt][1]);
                    float p2 = EXP2F(s0[nt][2]);
                    float p3 = EXP2F(s0[nt][3]);
                    l0 += (p0 + p1) + (p2 + p3);
                    P40[2 * nt] = pk2(p0, p1);
                    P40[2 * nt + 1] = pk2(p2, p3);
                }
            }
#pragma unroll
            for (int nt = 0; nt < 4; ++nt) {
                float p0 = EXP2F(s1[nt][0]);
                float p1 = EXP2F(s1[nt][1]);
                float p2 = EXP2F(s1[nt][2]);
                float p3 = EXP2F(s1[nt][3]);
                l1 += (p0 + p1) + (p2 + p3);
                P41[2 * nt] = pk2(p0, p1);
                P41[2 * nt + 1] = pk2(p2, p3);
            }
#pragma unroll
            for (int kk = 0; kk < 2; ++kk) {
                uint4 bw0, bw1;
                bw0.x = P40[2 * kk];
                bw0.y = P40[2 * kk + 1];
                bw0.z = P40[2 * kk + 4];
                bw0.w = P40[2 * kk + 5];
                bw1.x = P41[2 * kk];
                bw1.y = P41[2 * kk + 1];
                bw1.z = P41[2 * kk + 4];
                bw1.w = P41[2 * kk + 5];
                bf16x8 bp0 = __builtin_bit_cast(bf16x8, bw0);
                bf16x8 bp1 = __builtin_bit_cast(bf16x8, bw1);
#pragma unroll
                for (int mt = 0; mt < 4; ++mt) {
                    bf16x8 av = *(const bf16x8*)(Vs + (mt * 16 + col) * 72 + kk * 32 + quad * 8);
                    if (d0)
                        o0[mt] = __builtin_amdgcn_mfma_f32_16x16x32_bf16(av, bp0, o0[mt], 0, 0, 0);
                    o1[mt] = __builtin_amdgcn_mfma_f32_16x16x32_bf16(av, bp1, o1[mt], 0, 0, 0);
                }
            }
        }
        l0 += __shfl_xor(l0, 16);
        l0 += __shfl_xor(l0, 32);
        l1 += __shfl_xor(l1, 16);
        l1 += __shfl_xor(l1, 32);
        float inv0 = 1.0f / l0, inv1 = 1.0f / l1;
        u16* orow0 = O + (size_t)(b * 2048 + myq0) * 1024 + h * 64;
        u16* orow1 = O + (size_t)(b * 2048 + myq1) * 1024 + h * 64;
#pragma unroll
        for (int mt = 0; mt < 4; ++mt) {
            uint2 w0, w1;
            w0.x = pk2(o0[mt][0] * inv0, o0[mt][1] * inv0);
            w0.y = pk2(o0[mt][2] * inv0, o0[mt][3] * inv0);
            w1.x = pk2(o1[mt][0] * inv1, o1[mt][1] * inv1);
            w1.y = pk2(o1[mt][2] * inv1, o1[mt][3] * inv1);
            *(uint2*)(orow0 + mt * 16 + quad * 4) = w0;
            *(uint2*)(orow1 + mt * 16 + quad * 4) = w1;
        }
    }
}

// ---------------- output projection GEMM ----------------
__global__ __launch_bounds__(256) void k_gemm_proj(const u16* __restrict__ A,
                                                   const u16* __restrict__ Bt,
                                                   const float* __restrict__ bias,
                                                   float* __restrict__ out) {
    __shared__ __align__(16) u16 As[2 * 128 * 32];
    __shared__ __align__(16) u16 Bs[2 * 128 * 32];
    const int K = 1024;
    int tid = threadIdx.x;
    int lane = tid & 63, wave = tid >> 6;
    int col = lane & 15, quad = lane >> 4;
    int wm = wave >> 1, wn = wave & 1;
    int mBase = blockIdx.y * 128;
    int nBase = blockIdx.x * 128;
    f32x4 acc[4][4] = {};
    gemm_mainloop(A + (size_t)mBase * K, Bt + (size_t)nBase * K, K, As, Bs, tid, acc);
#pragma unroll
    for (int nt = 0; nt < 4; ++nt) {
        int n = nBase + wn * 64 + nt * 16 + col;
        float bv = bias[n];
#pragma unroll
        for (int mt = 0; mt < 4; ++mt) {
            int m = mBase + wm * 64 + mt * 16 + quad * 4;
#pragma unroll
            for (int r = 0; r < 4; ++r)
                out[(size_t)(m + r) * 1024 + n] = acc[mt][nt][r] + bv;
        }
    }
}

// ---------------- launch ----------------
// ws: x_bf@0 (16MB) wqkvT (6MB) wprojT (2MB) Qr Kr Vt AO (16MB each)
extern "C" void kernel_launch(void* const* d_in, const int* in_sizes, int n_in,
                              void* d_out, int out_size, void* d_ws, size_t ws_size,
                              hipStream_t stream) {
    const float* x = (const float*)d_in[0];
    const float* w_qkv = (const float*)d_in[1];
    const float* b_qkv = (const float*)d_in[2];
    const float* w_proj = (const float*)d_in[3];
    const float* b_proj = (const float*)d_in[4];
    float* out = (float*)d_out;
    char* ws = (char*)d_ws;
    u16* x_bf = (u16*)(ws);
    u16* wqkvT = (u16*)(ws + 16777216);
    u16* wprojT = (u16*)(ws + 23068672);
    u16* Qr = (u16*)(ws + 25165824);
    u16* Kr = (u16*)(ws + 41943040);
    u16* Vt = (u16*)(ws + 58720256);
    u16* AO = (u16*)(ws + 75497472);

    k_convert<<<4096, 256, 0, stream>>>(x, x_bf, 1048576);
    k_transpose_bf16<<<dim3(48, 16), 256, 0, stream>>>(w_qkv, wqkvT, 1024, 3072);
    k_transpose_bf16<<<dim3(16, 16), 256, 0, stream>>>(w_proj, wprojT, 1024, 1024);
    k_gemm_qkv_rope<<<dim3(24, 64), 256, 0, stream>>>(x_bf, wqkvT, b_qkv, Qr, Kr, Vt);
    k_attn<<<dim3(8, 64), 256, 0, stream>>>(Qr, Kr, Vt, AO);
    k_gemm_proj<<<dim3(8, 64), 256, 0, stream>>>(AO, wprojT, b_proj, out);
}